// Round 13
// baseline (361.190 us; speedup 1.0000x reference)
//
#include <hip/hip_runtime.h>
#include <hip/hip_bf16.h>
#include <hip/hip_fp16.h>

// Problem constants
#define TB 128
#define TT 500
#define TS 200
#define TE 100
#define TH 100
#define NCLS 400              // 2*S  (one-hot width of x)
#define NG   400              // 4*H  (gate width)
#define BT   (TB*TT)          // 64000 (b,t) pairs
#define BLK  448              // 7 waves x 4 tile-slots; block serves TWO batch elems

typedef _Float16 h8 __attribute__((ext_vector_type(8)));
union HU { float4 f4; __half hs[8]; };

__device__ __forceinline__ float frcp(float x) { return __builtin_amdgcn_rcpf(x); }
__device__ __forceinline__ float fsig(float x) { return frcp(1.f + __expf(-x)); }
__device__ __forceinline__ float ftanh(float x) { float e = __expf(2.f * x); return 1.f - 2.f * frcp(e + 1.f); }

// LDS-only barrier: drain lgkm (ds ops) but leave global loads/stores in flight.
__device__ __forceinline__ void barrier_lds() {
  asm volatile("s_waitcnt lgkmcnt(0)\n\ts_barrier" ::: "memory");
}

// quad-perm DPP cross-lane (within aligned 4-lane quads): ~VALU-speed, no LDS.
#define QXOR1(d, s) d = __int_as_float(__builtin_amdgcn_mov_dpp(__float_as_int(s), 177, 0xf, 0xf, true)) // [1,0,3,2]
#define QXOR2(d, s) d = __int_as_float(__builtin_amdgcn_mov_dpp(__float_as_int(s),  78, 0xf, 0xf, true)) // [2,3,0,1]
#define QXOR3(d, s) d = __int_as_float(__builtin_amdgcn_mov_dpp(__float_as_int(s),  27, 0xf, 0xf, true)) // [3,2,1,0]

// ---------------------------------------------------------------------------
// Kernel A: compress one-hot x (B,T,400) -> idx2 and q (B,T,200) -> qi.
// ---------------------------------------------------------------------------
__global__ void k_compress(const float* __restrict__ x, const float* __restrict__ q,
                           int* __restrict__ idx2, int* __restrict__ qi) {
  int gid  = blockIdx.x * blockDim.x + threadIdx.x;
  int wave = gid >> 6;
  int lane = threadIdx.x & 63;
  if (wave >= BT) return;

  const float4* xr = (const float4*)(x + (size_t)wave * NCLS);
  int li = -1;
  {
    float4 v = xr[lane];
    if (v.x > 0.5f) li = lane * 4 + 0;
    if (v.y > 0.5f) li = lane * 4 + 1;
    if (v.z > 0.5f) li = lane * 4 + 2;
    if (v.w > 0.5f) li = lane * 4 + 3;
    int ci = 64 + lane;
    if (ci < 100) {
      float4 w = xr[ci];
      if (w.x > 0.5f) li = ci * 4 + 0;
      if (w.y > 0.5f) li = ci * 4 + 1;
      if (w.z > 0.5f) li = ci * 4 + 2;
      if (w.w > 0.5f) li = ci * 4 + 3;
    }
  }
  #pragma unroll
  for (int off = 32; off; off >>= 1) li = max(li, __shfl_xor(li, off));

  const float4* qr = (const float4*)(q + (size_t)wave * TS);
  int qj = -1;
  if (lane < 50) {
    float4 v = qr[lane];
    if (v.x > 0.5f) qj = lane * 4 + 0;
    if (v.y > 0.5f) qj = lane * 4 + 1;
    if (v.z > 0.5f) qj = lane * 4 + 2;
    if (v.w > 0.5f) qj = lane * 4 + 3;
  }
  #pragma unroll
  for (int off = 32; off; off >>= 1) qj = max(qj, __shfl_xor(qj, off));

  if (lane == 0) { idx2[wave] = li; qi[wave] = qj; }
}

// ---------------------------------------------------------------------------
// Kernel A2: count features, fully parallel (one block per b, thread t).
// ---------------------------------------------------------------------------
__global__ void k_counts(const int* __restrict__ idx2, float2* __restrict__ ccg) {
  __shared__ int ids[TT];
  int b = blockIdx.x, tid = threadIdx.x;
  for (int i = tid; i < TT; i += 512) ids[i] = idx2[(size_t)b * TT + i];
  __syncthreads();
  if (tid < TT) {
    int s2 = ids[tid] & ~1;
    int c0 = 0, c1 = 0;
    for (int tp = 0; tp <= tid; ++tp) {
      int v = ids[tp];
      c0 += (v == s2);
      c1 += (v == s2 + 1);
    }
    ccg[(size_t)b * TT + tid] =
        make_float2(__logf(1.f + (float)c0), __logf(1.f + (float)c1));
  }
}

// ---------------------------------------------------------------------------
// Kernel B: precompute permuted tables for the MFMA layout.
// Permutation: orig gate-col j = g*100+u  ->  cp = (u>>2)*16 + (u&3)*4 + g
//  Gq[cls][cp], baseq/c0q/c1q[cp]  (f32)
//  Bfrag[(tile*4+ks)*64 + lane] = float4 of 8 f16: R[k][col(cp)] with
//     k = ks*32 + (lane>>4)*8 + j  (zero-pad k>=100), cp = tile*16+(lane&15)
//  WoT[s][k] = Wo[k][s]
// ---------------------------------------------------------------------------
__global__ void k_precompute(const float* __restrict__ Wx, const float* __restrict__ bx,
                             const float* __restrict__ K, const float* __restrict__ lb,
                             const float* __restrict__ Wo, const float* __restrict__ R,
                             float* __restrict__ Gq, float* __restrict__ baseq,
                             float* __restrict__ c0q, float* __restrict__ c1q,
                             float* __restrict__ WoT, float4* __restrict__ Bfrag) {
  int bid = blockIdx.x, tid = threadIdx.x;
  if (bid < NCLS) {
    if (tid < NG) {
      float acc = 0.0f;
      for (int e = 0; e < TE; ++e) acc = fmaf(Wx[bid * TE + e], K[e * NG + tid], acc);
      int g = tid / 100, u = tid % 100;
      int cp = (u >> 2) * 16 + (u & 3) * 4 + g;
      Gq[bid * NG + cp] = acc;
    }
  } else if (bid == NCLS) {
    if (tid < NG) {
      float acc = lb[tid];
      for (int e = 0; e < TE; ++e) acc = fmaf(bx[e], K[e * NG + tid], acc);
      int g = tid / 100, u = tid % 100;
      int cp = (u >> 2) * 16 + (u & 3) * 4 + g;
      baseq[cp] = acc;
      c0q[cp]   = K[100 * NG + tid] + K[102 * NG + tid];
      c1q[cp]   = K[101 * NG + tid] + K[102 * NG + tid];
    }
  } else {
    int id = (bid - NCLS - 1) * 512 + tid;
    if (id < TS * TH) {
      int s = id / TH, k = id % TH;
      WoT[id] = Wo[k * TS + s];
    } else {
      int id2 = id - TS * TH;
      if (id2 < 6400) {
        int lane = id2 & 63, ks = (id2 >> 6) & 3, tile = id2 >> 8;
        int qq = lane & 15, cgrp = lane >> 4;
        int col = (qq & 3) * 100 + tile * 4 + (qq >> 2);   // orig R column
        HU uu;
        #pragma unroll
        for (int j = 0; j < 8; ++j) {
          int k = ks * 32 + cgrp * 8 + j;
          float v = (k < TH) ? R[k * NG + col] : 0.0f;
          uu.hs[j] = __float2half_rn(v);
        }
        Bfrag[id2] = uu.f4;
      }
    }
  }
}

// ---------------------------------------------------------------------------
// Kernel C: LSTM recurrence, MATRIX pipe, TWO batch elements per block via
// M-split: A rows 0-7 = h(b0), rows 8-15 = h(b1) (A-layout row = lane&15,
// k = (lane>>4)*8+j). The SAME 16-MFMA block computes z for both elements.
// C row = (lane>>4)*4 + reg, so row-group cg holds elem = cg>>1; each lane
// activates its elem's TWO slots {cg&1, 2+(cg&1)}.
// R12 bug fixed here: hbuf has 512 halves but BLK=448 — the old
// `if (tid < 512)` init left halves 448..511 (elem1/parity1, incl. the
// k>=100 zero padding) uninitialized -> persistent garbage in b1's even-step
// MFMA contributions (absmax 2.7e-2). Init is now a strided loop.
// AGPR map unchanged from R11 (B-frags a0..a63 written once, acc a64..a79,
// zero a80..a83, clobber-reserved). ONE lgkm-only barrier per step; h in
// per-elem 2-row f16 LDS dbuf; G/cc prefetch depth-2; tiles>24 clamp to 24
// (valid dup arithmetic, writers masked by u<100). Grid: TB/2 = 64 blocks.
// ---------------------------------------------------------------------------
#define AW(N, V) asm volatile("v_accvgpr_write_b32 a" #N ", %0" :: "v"(V) : "a" #N)
#define AW4(N0,N1,N2,N3, F) do { AW(N0,(F).x); AW(N1,(F).y); AW(N2,(F).z); AW(N3,(F).w); } while(0)

#define CLOBS \
  "a0","a1","a2","a3","a4","a5","a6","a7","a8","a9","a10","a11","a12","a13", \
  "a14","a15","a16","a17","a18","a19","a20","a21","a22","a23","a24","a25",   \
  "a26","a27","a28","a29","a30","a31","a32","a33","a34","a35","a36","a37",   \
  "a38","a39","a40","a41","a42","a43","a44","a45","a46","a47","a48","a49",   \
  "a50","a51","a52","a53","a54","a55","a56","a57","a58","a59","a60","a61",   \
  "a62","a63","a64","a65","a66","a67","a68","a69","a70","a71","a72","a73",   \
  "a74","a75","a76","a77","a78","a79","a80","a81","a82","a83"

#define MFMA16(Z0,Z1,Z2,Z3, FA0,FA1,FA2,FA3)                          \
  asm volatile(                                                       \
    "s_nop 1\n\t"                                                     \
    "v_mfma_f32_16x16x32_f16 a[64:67], %4, a[0:3],   a[80:83]\n\t"    \
    "v_mfma_f32_16x16x32_f16 a[68:71], %4, a[16:19], a[80:83]\n\t"    \
    "v_mfma_f32_16x16x32_f16 a[72:75], %4, a[32:35], a[80:83]\n\t"    \
    "v_mfma_f32_16x16x32_f16 a[76:79], %4, a[48:51], a[80:83]\n\t"    \
    "v_mfma_f32_16x16x32_f16 a[64:67], %5, a[4:7],   a[64:67]\n\t"    \
    "v_mfma_f32_16x16x32_f16 a[68:71], %5, a[20:23], a[68:71]\n\t"    \
    "v_mfma_f32_16x16x32_f16 a[72:75], %5, a[36:39], a[72:75]\n\t"    \
    "v_mfma_f32_16x16x32_f16 a[76:79], %5, a[52:55], a[76:79]\n\t"    \
    "v_mfma_f32_16x16x32_f16 a[64:67], %6, a[8:11],  a[64:67]\n\t"    \
    "v_mfma_f32_16x16x32_f16 a[68:71], %6, a[24:27], a[68:71]\n\t"    \
    "v_mfma_f32_16x16x32_f16 a[72:75], %6, a[40:43], a[72:75]\n\t"    \
    "v_mfma_f32_16x16x32_f16 a[76:79], %6, a[56:59], a[76:79]\n\t"    \
    "v_mfma_f32_16x16x32_f16 a[64:67], %7, a[12:15], a[64:67]\n\t"    \
    "v_mfma_f32_16x16x32_f16 a[68:71], %7, a[28:31], a[68:71]\n\t"    \
    "v_mfma_f32_16x16x32_f16 a[72:75], %7, a[44:47], a[72:75]\n\t"    \
    "v_mfma_f32_16x16x32_f16 a[76:79], %7, a[60:63], a[76:79]\n\t"    \
    "s_nop 7\n\ts_nop 7\n\ts_nop 7\n\t"                               \
    "v_accvgpr_read_b32 %0, a64\n\t"                                  \
    "v_accvgpr_read_b32 %1, a68\n\t"                                  \
    "v_accvgpr_read_b32 %2, a72\n\t"                                  \
    "v_accvgpr_read_b32 %3, a76"                                      \
    : "=v"(Z0), "=v"(Z1), "=v"(Z2), "=v"(Z3)                          \
    : "v"(FA0), "v"(FA1), "v"(FA2), "v"(FA3)                          \
    : CLOBS)

__global__ void __attribute__((amdgpu_flat_work_group_size(BLK, BLK)))
k_lstm(const int* __restrict__ idx2, const float* __restrict__ Gq,
       const float* __restrict__ baseq, const float* __restrict__ c0q,
       const float* __restrict__ c1q, const float4* __restrict__ Bfrag,
       const float2* __restrict__ ccg, float* __restrict__ h_seq) {
  __shared__ __align__(16) __half hbuf[2][2][128];  // [elem][parity][padded row]
  __shared__ int idx_ls[2][TT];

  int bid = blockIdx.x, tid = threadIdx.x;
  int w = tid >> 6, lane = tid & 63;
  int q = lane & 15, g3 = lane & 3, cg = lane >> 4, qd = (lane >> 2) & 3;
  int eA   = (lane >> 3) & 1;          // A-fragment element (row = lane&15 split)
  int eact = cg >> 1;                  // activation element (C rows 4cg..4cg+3)
  int s1 = cg & 1, s2 = s1 + 2;        // this lane's two activation slots

  for (int i = tid; i < TT; i += BLK) {
    idx_ls[0][i] = idx2[(size_t)(2 * bid) * TT + i];
    idx_ls[1][i] = idx2[(size_t)(2 * bid + 1) * TT + i];
  }
  { __half* hb = &hbuf[0][0][0];
    for (int i = tid; i < 512; i += BLK) hb[i] = __float2half(0.f); }  // ALL 512 halves (R12 bug: tid<512 with 448 threads)

  // tiles: slot s of wave w -> 4w+s, clamped to 24 (dups masked at write)
  int tS0 = min(4 * w + 0, 24), tS1 = min(4 * w + 1, 24);
  int tS2 = min(4 * w + 2, 24), tS3 = min(4 * w + 3, 24);
  int tU1 = 4 * w + s1, tU2 = 4 * w + s2;           // unclamped (for write mask)
  int tC1 = min(tU1, 24), tC2 = min(tU2, 24);
  int gcol1 = tC1 * 16 + q, gcol2 = tC2 * 16 + q;
  float base1 = baseq[gcol1], c01 = c0q[gcol1], c11 = c1q[gcol1];
  float base2 = baseq[gcol2], c02 = c0q[gcol2], c12 = c1q[gcol2];
  int u1 = tU1 * 4 + qd, u2 = tU2 * 4 + qd;
  bool wr1 = (g3 == 0) && (u1 < TH);
  bool wr2 = (g3 == 0) && (u2 < TH);

  // ---- load B fragments into AGPRs (once; identical for both elements) ----
  {
    float4 f;
    f = Bfrag[(tS0 * 4 + 0) * 64 + lane]; AW4(0,1,2,3, f);
    f = Bfrag[(tS0 * 4 + 1) * 64 + lane]; AW4(4,5,6,7, f);
    f = Bfrag[(tS0 * 4 + 2) * 64 + lane]; AW4(8,9,10,11, f);
    f = Bfrag[(tS0 * 4 + 3) * 64 + lane]; AW4(12,13,14,15, f);
    f = Bfrag[(tS1 * 4 + 0) * 64 + lane]; AW4(16,17,18,19, f);
    f = Bfrag[(tS1 * 4 + 1) * 64 + lane]; AW4(20,21,22,23, f);
    f = Bfrag[(tS1 * 4 + 2) * 64 + lane]; AW4(24,25,26,27, f);
    f = Bfrag[(tS1 * 4 + 3) * 64 + lane]; AW4(28,29,30,31, f);
    f = Bfrag[(tS2 * 4 + 0) * 64 + lane]; AW4(32,33,34,35, f);
    f = Bfrag[(tS2 * 4 + 1) * 64 + lane]; AW4(36,37,38,39, f);
    f = Bfrag[(tS2 * 4 + 2) * 64 + lane]; AW4(40,41,42,43, f);
    f = Bfrag[(tS2 * 4 + 3) * 64 + lane]; AW4(44,45,46,47, f);
    f = Bfrag[(tS3 * 4 + 0) * 64 + lane]; AW4(48,49,50,51, f);
    f = Bfrag[(tS3 * 4 + 1) * 64 + lane]; AW4(52,53,54,55, f);
    f = Bfrag[(tS3 * 4 + 2) * 64 + lane]; AW4(56,57,58,59, f);
    f = Bfrag[(tS3 * 4 + 3) * 64 + lane]; AW4(60,61,62,63, f);
    float zf = 0.0f;
    AW(80, zf); AW(81, zf); AW(82, zf); AW(83, zf);
  }
  asm volatile("" ::: CLOBS);    // a0..a83 reserved for the whole kernel

  float c_reg1 = 0.f, c_reg2 = 0.f;
  __syncthreads();               // idx_ls, hbuf visible

  const int* idxe = idx_ls[eact];
  const float2* ccg_e = ccg + (size_t)(2 * bid + eact) * TT;
  float* hout_e = h_seq + (size_t)(2 * bid + eact) * TT * TH;

  float g1A = Gq[(size_t)idxe[0] * NG + gcol1];
  float g2A = Gq[(size_t)idxe[0] * NG + gcol2];
  float g1B = Gq[(size_t)idxe[1] * NG + gcol1];
  float g2B = Gq[(size_t)idxe[1] * NG + gcol2];
  float2 ccA = ccg_e[0], ccB = ccg_e[1];

  #define ACT(ZZ, CREG, HN)                                                    \
  { float arg = (g3 == 2) ? ((ZZ) + (ZZ)) : (-(ZZ));                           \
    float E = __expf(arg);                                                     \
    float r = frcp(1.f + E);                                                   \
    float act = (g3 == 2) ? fmaf(-2.f, r, 1.f) : r;                            \
    float x1, x2, x3;                                                          \
    QXOR1(x1, act); QXOR2(x2, act); QXOR3(x3, act);                            \
    (CREG) = fmaf(x1, (CREG), act * x2);   /* g3==0 lanes: ai=act af=x1 ag=x2 */\
    (HN) = x3 * ftanh(CREG); }

  #define STEP(T_, PAR, G1, G2, CCV)                                           \
  { const int t_ = (T_);                                                       \
    barrier_lds();               /* h(t-1) visible; VMEM stays in flight */    \
    const h8* hrowA = (const h8*)(&hbuf[eA][(PAR) ^ 1][0]);                    \
    h8 fa0 = hrowA[cg], fa1 = hrowA[4 + cg], fa2 = hrowA[8 + cg], fa3 = hrowA[12 + cg]; \
    float z0, z1, z2, z3;                                                      \
    MFMA16(z0, z1, z2, z3, fa0, fa1, fa2, fa3);                                \
    float zs1 = s1 ? z1 : z0;                    /* slot cg&1 */               \
    float zs2 = s1 ? z3 : z2;                    /* slot 2+(cg&1) */           \
    float2 cc = (CCV);                                                         \
    int tnx = (t_ + 2 < TT) ? t_ + 2 : TT - 1;                                 \
    float zz1 = zs1 + (G1) + base1 + cc.x * c01 + cc.y * c11;                  \
    float zz2 = zs2 + (G2) + base2 + cc.x * c02 + cc.y * c12;                  \
    int idn = idxe[tnx];                                                       \
    (G1) = Gq[(size_t)idn * NG + gcol1];         /* depth-2 refill */          \
    (G2) = Gq[(size_t)idn * NG + gcol2];                                       \
    (CCV) = ccg_e[tnx];                                                        \
    float hn1, hn2;                                                            \
    ACT(zz1, c_reg1, hn1);                                                     \
    ACT(zz2, c_reg2, hn2);                                                     \
    if (wr1) {                                                                 \
      hbuf[eact][PAR][u1] = __float2half_rn(hn1);                              \
      hout_e[(size_t)t_ * TH + u1] = hn1;        /* un-drained store */        \
    }                                                                          \
    if (wr2) {                                                                 \
      hbuf[eact][PAR][u2] = __float2half_rn(hn2);                              \
      hout_e[(size_t)t_ * TH + u2] = hn2;                                      \
    }                                                                          \
  }

  for (int t2 = 0; t2 < TT; t2 += 2) {
    STEP(t2, 0, g1A, g2A, ccA);      // even t: read hbuf[*][1], write hbuf[*][0]
    STEP(t2 + 1, 1, g1B, g2B, ccB);  // odd  t: read hbuf[*][0], write hbuf[*][1]
  }
  #undef STEP
  #undef ACT
}

// ---------------------------------------------------------------------------
// Kernel D: out[b,t] = sigmoid( h_seq[b,t] . WoT[qi[b,t]] + bo[qi] )
// ---------------------------------------------------------------------------
__global__ void k_out(const float* __restrict__ h_seq, const float* __restrict__ WoT,
                      const float* __restrict__ bo, const int* __restrict__ qi,
                      float* __restrict__ out) {
  int gid  = blockIdx.x * blockDim.x + threadIdx.x;
  int wave = gid >> 6;
  int lane = threadIdx.x & 63;
  if (wave >= BT) return;
  int s = qi[wave];
  const float4* h4 = (const float4*)(h_seq + (size_t)wave * TH);
  const float4* w4 = (const float4*)(WoT + (size_t)s * TH);
  float acc = 0.0f;
  if (lane < TH / 4) {
    float4 h = h4[lane];
    float4 w = w4[lane];
    acc = h.x * w.x + h.y * w.y + h.z * w.z + h.w * w.w;
  }
  #pragma unroll
  for (int off = 32; off; off >>= 1) acc += __shfl_xor(acc, off);
  if (lane == 0) out[wave] = fsig(acc + bo[s]);
}

// ---------------------------------------------------------------------------
extern "C" void kernel_launch(void* const* d_in, const int* in_sizes, int n_in,
                              void* d_out, int out_size, void* d_ws, size_t ws_size,
                              hipStream_t stream) {
  const float* x    = (const float*)d_in[0];
  // d_in[1] = delta (unused by the reference)
  const float* q    = (const float*)d_in[2];
  const float* Wx   = (const float*)d_in[3];
  const float* bx   = (const float*)d_in[4];
  const float* K    = (const float*)d_in[5];   // lstm_k (103,400)
  const float* R    = (const float*)d_in[6];   // lstm_rk (100,400)
  const float* lb   = (const float*)d_in[7];   // lstm_b (400)
  const float* Wo   = (const float*)d_in[8];   // (100,200)
  const float* bo   = (const float*)d_in[9];   // (200)
  float* out = (float*)d_out;

  // workspace layout (floats)
  float* ws = (float*)d_ws;
  float*  Gq     = ws;                      // 160000
  float*  baseq  = ws + 160000;             // 400
  float*  c0q    = ws + 160400;             // 400
  float*  c1q    = ws + 160800;             // 400
  float*  WoT    = ws + 161200;             // 20000
  float4* Bfrag  = (float4*)(ws + 181200);  // 6400 float4 = 25600 floats
  int*    idx2   = (int*)(ws + 206800);     // 64000
  int*    qi     = (int*)(ws + 270800);     // 64000
  float2* ccg    = (float2*)(ws + 334800);  // 64000 float2 = 128000 floats
  float*  h_seq  = ws + 462800;             // 6,400,000
  // total: 6,862,800 floats = 27.5 MB

  // A: compress one-hots
  k_compress<<<BT / 4, 256, 0, stream>>>(x, q, idx2, qi);

  // A2: parallel count features
  k_counts<<<TB, 512, 0, stream>>>(idx2, ccg);

  // B: precompute permuted tables + MFMA B-fragments
  int tail_blocks = (TS * TH + 6400 + 511) / 512;        // 52
  k_precompute<<<NCLS + 1 + tail_blocks, 512, 0, stream>>>(Wx, bx, K, lb, Wo, R,
                                                           Gq, baseq, c0q, c1q, WoT, Bfrag);

  // C: sequential LSTM, TWO batch elements per block (M-split MFMA)
  k_lstm<<<TB / 2, BLK, 0, stream>>>(idx2, Gq, baseq, c0q, c1q, Bfrag, ccg, h_seq);

  // D: gather + dot + sigmoid
  k_out<<<BT / 4, 256, 0, stream>>>(h_seq, WoT, bo, qi, out);
}